// Round 11
// baseline (99.031 us; speedup 1.0000x reference)
//
#include <hip/hip_runtime.h>
#include <hip/hip_bf16.h>
#include <hip/hip_fp16.h>
#include <stdint.h>

typedef __attribute__((ext_vector_type(8))) _Float16 f16x8;
typedef __attribute__((ext_vector_type(4))) float f32x4;
typedef __attribute__((ext_vector_type(4))) int i32x4;

#define GLD_LDS16(g, l) __builtin_amdgcn_global_load_lds( \
    (const __attribute__((address_space(1))) uint32_t*)(g), \
    (__attribute__((address_space(3))) uint32_t*)(l), 16, 0, 0)

// ---------------- W fp32 -> fp16 (into workspace), 512x2048 -------------
__global__ __launch_bounds__(256) void k_cvt_w(const float* __restrict__ W,
                                               _Float16* __restrict__ Wh) {
  int i = (blockIdx.x * 256 + threadIdx.x) * 8;  // 1048576 elems total
  float4 a = *(const float4*)(W + i);
  float4 b = *(const float4*)(W + i + 4);
  union { _Float16 h[8]; i32x4 v; } u;
  u.h[0] = (_Float16)a.x; u.h[1] = (_Float16)a.y;
  u.h[2] = (_Float16)a.z; u.h[3] = (_Float16)a.w;
  u.h[4] = (_Float16)b.x; u.h[5] = (_Float16)b.y;
  u.h[6] = (_Float16)b.z; u.h[7] = (_Float16)b.w;
  *(i32x4*)(Wh + i) = u.v;
}

__device__ inline float softplus_f(float x) {
  float e = __expf(-fabsf(x));
  return fmaxf(x, 0.f) + __logf(1.f + e);
}

// ---- fused GEMM(fp16 MFMA) + softplus-diff partial: SMALL-BLOCK m97 ----
// Tile 64 rows x 128 cols (N-split 4), BK=32, 64 steps. 128 thr = 2 waves,
// each wave = 64x64 (acc 4x4, 16 MFMA/step). Grid 1024 -> 4 independent
// blocks/CU (LDS 24KB): barriers sync only 2 waves; co-resident blocks
// absorb drain stalls (m114/m97 regime). Dbuf LDS, ONE __syncthreads/step,
// stage-before-compute, zero asm waits.
// Swizzle (both tiles, 64B rows of 4x16B slots): phys slot of logical
// chunk c at row r is (c + (r>>1)) & 3  -> bank-group coverage exactly
// 2x uniform for b128 frag reads AND the A ds_writes (conflict-free).
__global__ __launch_bounds__(128, 3) void k_main(
    const float* __restrict__ X,      // [16384][2048]
    const _Float16* __restrict__ Wh,  // [512][2048]
    const float* __restrict__ U,      // [512][2]
    const float* __restrict__ hb,     // [512]
    float* __restrict__ Dp) {         // [4][16384] partial logit-diffs
  __shared__ __align__(16) _Float16 Ah[2][64 * 32];   // 2 x 4 KB
  __shared__ __align__(16) _Float16 Bs[2][128 * 32];  // 2 x 8 KB
  __shared__ float sD[64];

  const int t = threadIdx.x;   // 0..127
  const int lane = t & 63;
  const int wid = t >> 6;      // 0..1: wave owns cols [wid*64, wid*64+64)
  const int bx = blockIdx.x;
  const int bm0 = (bx >> 2) * 64;
  const int nq = bx & 3;
  const int bn0 = nq * 128;
  const int lrow = lane & 15, lq = lane >> 4;

  if (t < 64) sD[t] = 0.f;

  f32x4 acc[4][4];
#pragma unroll
  for (int m = 0; m < 4; ++m)
#pragma unroll
    for (int n = 0; n < 4; ++n) acc[m][n] = (f32x4){0.f, 0.f, 0.f, 0.f};

  // ---- A staging: thread -> row t>>1 (0..63), k-half t&1 (16 fp32) ----
  const int ar = t >> 1;
  const float* xsrc = X + (size_t)(bm0 + ar) * 2048 + (t & 1) * 16;
  const int ac0 = 2 * (t & 1);  // first logical 16B chunk this thread writes
  const int aw0 = ar * 64 + (((ac0 + (ar >> 1)) & 3) << 4);
  const int aw1 = ar * 64 + (((ac0 + 1 + (ar >> 1)) & 3) << 4);

  // ---- B staging: wave stages its own 64 cols; 4 gld_lds of 1KB ----
  // issue j covers cols [wid*64 + j*16, +16); lane l -> col +(l>>2),
  // phys slot l&3 holds logical chunk ((l&3) - ((l>>3)&3)) & 3.
  const int bcol = wid * 64 + (lane >> 2);  // + j*16 per issue
  const int bchunk = ((lane & 3) - ((lane >> 3) & 3)) & 3;
  const _Float16* bsrc = Wh + (size_t)(bn0 + bcol) * 2048 + bchunk * 8;
  char* const bdst0 = (char*)&Bs[0][0] + wid * 4096 + (lane >> 4) * 1024;
  char* const bdst1 = (char*)&Bs[1][0] + wid * 4096 + (lane >> 4) * 1024;
  // NOTE: dest for issue j = wave base + j*1024 + lane*16; we fold the
  // per-issue offset below. (lane>>4)*1024 is NOT part of dest; see ISSUE_B.

  f32x4 araw[4];  // 16 fp32 = this thread's A slice of one K-step

#define ISSUE_B(DQ, KB) do {                                               \
    _Pragma("unroll") for (int j = 0; j < 4; ++j)                          \
      GLD_LDS16(bsrc + (size_t)(j * 16) * 2048 + (size_t)(KB) * 32,        \
                (char*)(DQ) + wid * 4096 + j * 1024);                      \
  } while (0)

#define LOAD_A(KA) do {                                                    \
    _Pragma("unroll") for (int c = 0; c < 4; ++c)                          \
      araw[c] = *(const f32x4*)(xsrc + (size_t)(KA) * 32 + c * 4);         \
  } while (0)

#define CVT_A(Q) do {                                                      \
    f16x8 h0, h1;                                                          \
    _Pragma("unroll") for (int j = 0; j < 4; ++j) {                        \
      h0[j] = (_Float16)araw[0][j]; h0[j + 4] = (_Float16)araw[1][j];      \
      h1[j] = (_Float16)araw[2][j]; h1[j + 4] = (_Float16)araw[3][j];      \
    }                                                                      \
    *(f16x8*)((char*)&Ah[Q][0] + aw0) = h0;                                \
    *(f16x8*)((char*)&Ah[Q][0] + aw1) = h1;                                \
  } while (0)

#define COMPUTE(P) do {                                                    \
    f16x8 fa[4], fb[4];                                                    \
    _Pragma("unroll") for (int mf = 0; mf < 4; ++mf) {                     \
      int r = mf * 16 + lrow;                                              \
      fa[mf] = *(const f16x8*)((const char*)&Ah[P][0] + r * 64 +           \
                               (((lq + (r >> 1)) & 3) << 4));              \
    }                                                                      \
    _Pragma("unroll") for (int nf = 0; nf < 4; ++nf) {                     \
      int c = wid * 64 + nf * 16 + lrow;                                   \
      fb[nf] = *(const f16x8*)((const char*)&Bs[P][0] + c * 64 +           \
                               (((lq + (c >> 1)) & 3) << 4));              \
    }                                                                      \
    __builtin_amdgcn_s_setprio(1);                                         \
    _Pragma("unroll") for (int mf = 0; mf < 4; ++mf)                       \
      _Pragma("unroll") for (int nf = 0; nf < 4; ++nf)                     \
        acc[mf][nf] = __builtin_amdgcn_mfma_f32_16x16x32_f16(              \
            fa[mf], fb[nf], acc[mf][nf], 0, 0, 0);                         \
    __builtin_amdgcn_s_setprio(0);                                         \
  } while (0)

  // One step: stage tile KT+1 into Q, compute tile KT from P, one barrier.
#define STEP(KT, P, Q) do {                                                \
    const int kb_ = ((KT) + 1 > 63) ? 63 : (KT) + 1;                       \
    const int ka_ = ((KT) + 2 > 63) ? 63 : (KT) + 2;                       \
    ISSUE_B(&Bs[Q][0], kb_);                                               \
    CVT_A(Q); /* araw holds A(KT+1) on entry */                            \
    LOAD_A(ka_);                                                           \
    COMPUTE(P);                                                            \
    __syncthreads();                                                       \
  } while (0)

  // ---- prologue: tile 0 -> LDS[0]; araw <- A(1) ----
  ISSUE_B(&Bs[0][0], 0);
  LOAD_A(0);
  CVT_A(0);
  LOAD_A(1);
  __syncthreads();

  for (int kt = 0; kt < 64; kt += 2) {
    STEP(kt, 0, 1);
    STEP(kt + 1, 1, 0);
  }
#undef STEP
#undef COMPUTE
#undef CVT_A
#undef LOAD_A
#undef ISSUE_B

  // ---- epilogue: softplus-difference partial for this N-quarter ----
  // acc[mf][nf][r]: row = bm0 + mf*16 + lq*4 + r
  //                 col = bn0 + wid*64 + nf*16 + lrow
  float dpart[16];
#pragma unroll
  for (int i = 0; i < 16; ++i) dpart[i] = 0.f;
#pragma unroll
  for (int nf = 0; nf < 4; ++nf) {
    int h = bn0 + wid * 64 + nf * 16 + lrow;
    float hbv = hb[h];
    float u0 = U[2 * h], u1 = U[2 * h + 1];
#pragma unroll
    for (int mf = 0; mf < 4; ++mf)
#pragma unroll
      for (int r = 0; r < 4; ++r) {
        float pf = acc[mf][nf][r] + hbv;
        dpart[mf * 4 + r] += softplus_f(pf + u0) - softplus_f(pf + u1);
      }
  }
#pragma unroll
  for (int i = 0; i < 16; ++i) {
    float v = dpart[i];
    v += __shfl_xor(v, 1);
    v += __shfl_xor(v, 2);
    v += __shfl_xor(v, 4);
    v += __shfl_xor(v, 8);
    dpart[i] = v;
  }
  if (lrow == 0) {
#pragma unroll
    for (int mf = 0; mf < 4; ++mf)
#pragma unroll
      for (int r = 0; r < 4; ++r)
        atomicAdd(&sD[mf * 16 + lq * 4 + r], dpart[mf * 4 + r]);
  }
  __syncthreads();
  if (t < 64) Dp[nq * 16384 + bm0 + t] = sD[t];
}

// ---- combine the four N-quarter partials + sigmoid ----
__global__ __launch_bounds__(256) void k_final(const float* __restrict__ Dp,
                                               const float* __restrict__ yb,
                                               float* __restrict__ out) {
  int i = blockIdx.x * 256 + threadIdx.x;  // 0..16383
  float D = Dp[i] + Dp[16384 + i] + Dp[2 * 16384 + i] + Dp[3 * 16384 + i] +
            yb[0] - yb[1];  // logit0 - logit1
  float e = __expf(-D);
  float o0 = 1.f / (1.f + e);
  float o1 = e * o0;
  *(float2*)(out + (size_t)i * 2) = make_float2(o0, o1);
}

extern "C" void kernel_launch(void* const* d_in, const int* in_sizes, int n_in,
                              void* d_out, int out_size, void* d_ws,
                              size_t ws_size, hipStream_t stream) {
  const float* X = (const float*)d_in[0];
  const float* W = (const float*)d_in[1];
  const float* U = (const float*)d_in[2];
  const float* hb = (const float*)d_in[3];
  const float* yb = (const float*)d_in[4];
  float* out = (float*)d_out;
  _Float16* Wh = (_Float16*)d_ws;                       // 2 MB
  float* Dp = (float*)((char*)d_ws + 2 * 1024 * 1024);  // 256 KB partials

  hipLaunchKernelGGL(k_cvt_w, dim3(512), dim3(256), 0, stream, W, Wh);
  hipLaunchKernelGGL(k_main, dim3(1024), dim3(128), 0, stream, X, Wh, U, hb,
                     Dp);
  hipLaunchKernelGGL(k_final, dim3(64), dim3(256), 0, stream, Dp, yb, out);
}

// Round 12
// 85.090 us; speedup vs baseline: 1.1638x; 1.1638x over previous
//
#include <hip/hip_runtime.h>
#include <hip/hip_bf16.h>
#include <hip/hip_fp16.h>
#include <stdint.h>

typedef __attribute__((ext_vector_type(8))) _Float16 f16x8;
typedef __attribute__((ext_vector_type(4))) float f32x4;
typedef __attribute__((ext_vector_type(4))) int i32x4;

#define GLD_LDS16(g, l) __builtin_amdgcn_global_load_lds( \
    (const __attribute__((address_space(1))) uint32_t*)(g), \
    (__attribute__((address_space(3))) uint32_t*)(l), 16, 0, 0)

// ---------------- W fp32 -> fp16 (into workspace), 512x2048 -------------
__global__ __launch_bounds__(256) void k_cvt_w(const float* __restrict__ W,
                                               _Float16* __restrict__ Wh) {
  int i = (blockIdx.x * 256 + threadIdx.x) * 8;  // 1048576 elems total
  float4 a = *(const float4*)(W + i);
  float4 b = *(const float4*)(W + i + 4);
  union { _Float16 h[8]; i32x4 v; } u;
  u.h[0] = (_Float16)a.x; u.h[1] = (_Float16)a.y;
  u.h[2] = (_Float16)a.z; u.h[3] = (_Float16)a.w;
  u.h[4] = (_Float16)b.x; u.h[5] = (_Float16)b.y;
  u.h[6] = (_Float16)b.z; u.h[7] = (_Float16)b.w;
  *(i32x4*)(Wh + i) = u.v;
}

__device__ inline float softplus_f(float x) {
  float e = __expf(-fabsf(x));
  return fmaxf(x, 0.f) + __logf(1.f + e);
}

// ---- fused GEMM(fp16 MFMA) + softplus-diff partial, FAT TILE, UNPINNED ----
// R10 geometry (proven: 0 bank conflicts, absmax 0.0156): block 128x256
// (N-split 2), BK=64, 32 K-steps, 8 waves 2Mx4N, wave-tile 64x64.
// R13 delta vs R10 (m141/m190 lessons): NO sched_barrier(0), NO setprio,
// NO mid-step asm wait -- compiler schedules/waits IR loads itself (m97
// discipline). Only per-step sync: s_waitcnt vmcnt(4) lgkmcnt(0) (drain B
// gld_lds + A ds_write; A(t+2) IR loads stay in flight) + raw s_barrier.
__global__ __launch_bounds__(512, 2) void k_main(
    const float* __restrict__ X,      // [16384][2048]
    const _Float16* __restrict__ Wh,  // [512][2048]
    const float* __restrict__ U,      // [512][2]
    const float* __restrict__ hb,     // [512]
    float* __restrict__ Dp) {         // [2][16384] partial logit-diffs
  __shared__ __align__(16) _Float16 As[2][128 * 64];  // 2 x 16 KB
  __shared__ __align__(16) _Float16 Bs[2][256 * 64];  // 2 x 32 KB
  __shared__ float sD[128];

  const int t = threadIdx.x;
  const int lane = t & 63;
  const int wid = t >> 6;   // 0..7
  const int wm = wid >> 2;  // 0..1 (M half)
  const int wn = wid & 3;   // 0..3 (N quarter)
  const int bx = blockIdx.x;
  const int bm0 = (bx >> 1) * 128;
  const int nhalf = bx & 1;
  const int bn0 = nhalf * 256;
  const int lrow = lane & 15, lq = lane >> 4;

  if (t < 128) sD[t] = 0.f;
  __syncthreads();

  f32x4 acc[4][4];
#pragma unroll
  for (int m = 0; m < 4; ++m)
#pragma unroll
    for (int n = 0; n < 4; ++n) acc[m][n] = (f32x4){0.f, 0.f, 0.f, 0.f};

  // A staging: thread -> row t>>2 (0..127), k-chunk16 t&3. Writes 2 f16x8
  // at slots {2c, 2c+1} ^ (row&7)  (proven swizzle family, R4-R10).
  const int arow = t >> 2, ach = t & 3;
  const float* xsrc = X + (size_t)(bm0 + arow) * 2048 + ach * 16;
  const int c0 = ach * 2;
  const int aw0 = arow * 128 + (((c0) ^ (arow & 7)) << 4);
  const int aw1 = arow * 128 + (((c0 + 1) ^ (arow & 7)) << 4);

  // B staging: wave wid covers rows [wid*32, wid*32+32), 4 gld_lds of 1KB.
  // Pre-swizzled source (m173): phys slot s8 of row l8 holds chunk s8^l8.
  const int l8 = lane >> 3, s8 = lane & 7;
  const _Float16* bsrc =
      Wh + (size_t)(bn0 + wid * 32 + l8) * 2048 + (s8 ^ l8) * 8;
  char* const bd0 = (char*)&Bs[0][0] + wid * 4096;
  char* const bd1 = (char*)&Bs[1][0] + wid * 4096;

  f32x4 arA[4], arB[4];  // A fp32 raw, two named sets (static idx only)

#define CVT_WRITE_A(ARC, Q) do {                                           \
    f16x8 hv0, hv1;                                                        \
    _Pragma("unroll") for (int j = 0; j < 4; ++j) {                        \
      hv0[j] = (_Float16)ARC[0][j]; hv0[j + 4] = (_Float16)ARC[1][j];      \
      hv1[j] = (_Float16)ARC[2][j]; hv1[j + 4] = (_Float16)ARC[3][j];      \
    }                                                                      \
    *(f16x8*)((char*)&As[Q][0] + aw0) = hv0;                               \
    *(f16x8*)((char*)&As[Q][0] + aw1) = hv1;                               \
  } while (0)

  // One K-step (KT): stage B(KT+1)->Q, load A(KT+2)->ARL, cvt A(KT+1)->Q,
  // compute tile KT from P. Compiler free to interleave everything; the
  // only fence is the tail wait+barrier.
#define STEP(KT, P, Q, ARL, ARC, BDQ) do {                                 \
    const int kb_ = ((KT) + 1 > 31) ? 31 : (KT) + 1;                       \
    const int ka_ = ((KT) + 2 > 31) ? 31 : (KT) + 2;                       \
    _Pragma("unroll") for (int i = 0; i < 4; ++i)                          \
      GLD_LDS16(bsrc + (size_t)i * 16384 + (size_t)kb_ * 64,               \
                (BDQ) + i * 1024);                                         \
    _Pragma("unroll") for (int c = 0; c < 4; ++c)                          \
      ARL[c] = *(const f32x4*)(xsrc + (size_t)ka_ * 64 + c * 4);           \
    CVT_WRITE_A(ARC, Q);                                                   \
    f16x8 fa[4][2], fb[4][2];                                              \
    _Pragma("unroll") for (int mf = 0; mf < 4; ++mf) {                     \
      int row = wm * 64 + mf * 16 + lrow;                                  \
      _Pragma("unroll") for (int ks = 0; ks < 2; ++ks) {                   \
        int off = row * 128 + (((ks * 4 + lq) ^ (row & 7)) << 4);          \
        fa[mf][ks] = *(const f16x8*)((const char*)&As[P][0] + off);        \
      }                                                                    \
    }                                                                      \
    _Pragma("unroll") for (int nf = 0; nf < 4; ++nf) {                     \
      int row = wn * 64 + nf * 16 + lrow;                                  \
      _Pragma("unroll") for (int ks = 0; ks < 2; ++ks) {                   \
        int off = row * 128 + (((ks * 4 + lq) ^ (row & 7)) << 4);          \
        fb[nf][ks] = *(const f16x8*)((const char*)&Bs[P][0] + off);        \
      }                                                                    \
    }                                                                      \
    _Pragma("unroll") for (int ks = 0; ks < 2; ++ks)                       \
      _Pragma("unroll") for (int mf = 0; mf < 4; ++mf)                     \
        _Pragma("unroll") for (int nf = 0; nf < 4; ++nf)                   \
          acc[mf][nf] = __builtin_amdgcn_mfma_f32_16x16x32_f16(            \
              fa[mf][ks], fb[nf][ks], acc[mf][nf], 0, 0, 0);               \
    asm volatile("s_waitcnt vmcnt(4) lgkmcnt(0)" ::: "memory");            \
    __builtin_amdgcn_s_barrier();                                          \
  } while (0)

  // ---- prologue: A(0)->regsA, B(0)->buf0, A(1)->regsB; cvt A(0)->As[0] --
#pragma unroll
  for (int c = 0; c < 4; ++c) arA[c] = *(const f32x4*)(xsrc + c * 4);
#pragma unroll
  for (int i = 0; i < 4; ++i)
    GLD_LDS16(bsrc + (size_t)i * 16384, bd0 + i * 1024);
#pragma unroll
  for (int c = 0; c < 4; ++c) arB[c] = *(const f32x4*)(xsrc + 64 + c * 4);
  CVT_WRITE_A(arA, 0);
  asm volatile("s_waitcnt vmcnt(4) lgkmcnt(0)" ::: "memory");
  __builtin_amdgcn_s_barrier();
  // entry state: outstanding [A(1)x4]; As[0], Bs[0] staged.

  for (int kt = 0; kt < 32; kt += 2) {
    STEP(kt, 0, 1, arA, arB, bd1);      // consume tile kt
    STEP(kt + 1, 1, 0, arB, arA, bd0);  // consume tile kt+1
  }
#undef STEP
#undef CVT_WRITE_A

  // ---- epilogue: softplus-difference partial for this N-half ----
  // acc[mf][nf][r]: row = bm0 + wm*64 + mf*16 + lq*4 + r
  //                 col = bn0 + wn*64 + nf*16 + lrow
  float dpart[16];
#pragma unroll
  for (int i = 0; i < 16; ++i) dpart[i] = 0.f;
#pragma unroll
  for (int nf = 0; nf < 4; ++nf) {
    int h = bn0 + wn * 64 + nf * 16 + lrow;
    float hbv = hb[h];
    float u0 = U[2 * h], u1 = U[2 * h + 1];
#pragma unroll
    for (int mf = 0; mf < 4; ++mf)
#pragma unroll
      for (int r = 0; r < 4; ++r) {
        float pf = acc[mf][nf][r] + hbv;
        dpart[mf * 4 + r] += softplus_f(pf + u0) - softplus_f(pf + u1);
      }
  }
#pragma unroll
  for (int i = 0; i < 16; ++i) {
    float v = dpart[i];
    v += __shfl_xor(v, 1);
    v += __shfl_xor(v, 2);
    v += __shfl_xor(v, 4);
    v += __shfl_xor(v, 8);
    dpart[i] = v;
  }
  if (lrow == 0) {
#pragma unroll
    for (int mf = 0; mf < 4; ++mf)
#pragma unroll
      for (int r = 0; r < 4; ++r)
        atomicAdd(&sD[wm * 64 + mf * 16 + lq * 4 + r], dpart[mf * 4 + r]);
  }
  __syncthreads();
  if (t < 128) Dp[nhalf * 16384 + bm0 + t] = sD[t];
}

// ---- combine the two N-half partials + sigmoid ----
__global__ __launch_bounds__(256) void k_final(const float* __restrict__ Dp,
                                               const float* __restrict__ yb,
                                               float* __restrict__ out) {
  int i = blockIdx.x * 256 + threadIdx.x;  // 0..16383
  float D = Dp[i] + Dp[16384 + i] + yb[0] - yb[1];  // logit0 - logit1
  float e = __expf(-D);
  float o0 = 1.f / (1.f + e);
  float o1 = e * o0;
  *(float2*)(out + (size_t)i * 2) = make_float2(o0, o1);
}

extern "C" void kernel_launch(void* const* d_in, const int* in_sizes, int n_in,
                              void* d_out, int out_size, void* d_ws,
                              size_t ws_size, hipStream_t stream) {
  const float* X = (const float*)d_in[0];
  const float* W = (const float*)d_in[1];
  const float* U = (const float*)d_in[2];
  const float* hb = (const float*)d_in[3];
  const float* yb = (const float*)d_in[4];
  float* out = (float*)d_out;
  _Float16* Wh = (_Float16*)d_ws;                       // 2 MB
  float* Dp = (float*)((char*)d_ws + 2 * 1024 * 1024);  // 128 KB partials

  hipLaunchKernelGGL(k_cvt_w, dim3(512), dim3(256), 0, stream, W, Wh);
  hipLaunchKernelGGL(k_main, dim3(256), dim3(512), 0, stream, X, Wh, U, hb, Dp);
  hipLaunchKernelGGL(k_final, dim3(64), dim3(256), 0, stream, Dp, yb, out);
}

// Round 13
// 67.861 us; speedup vs baseline: 1.4593x; 1.2539x over previous
//
#include <hip/hip_runtime.h>
#include <hip/hip_bf16.h>
#include <hip/hip_fp16.h>
#include <stdint.h>

typedef __attribute__((ext_vector_type(8))) _Float16 f16x8;
typedef __attribute__((ext_vector_type(4))) float f32x4;
typedef __attribute__((ext_vector_type(4))) int i32x4;

#define GLD_LDS16(g, l) __builtin_amdgcn_global_load_lds( \
    (const __attribute__((address_space(1))) uint32_t*)(g), \
    (__attribute__((address_space(3))) uint32_t*)(l), 16, 0, 0)

// ---------------- W fp32 -> fp16 (into workspace), 512x2048 -------------
__global__ __launch_bounds__(256) void k_cvt_w(const float* __restrict__ W,
                                               _Float16* __restrict__ Wh) {
  int i = (blockIdx.x * 256 + threadIdx.x) * 8;  // 1048576 elems total
  float4 a = *(const float4*)(W + i);
  float4 b = *(const float4*)(W + i + 4);
  union { _Float16 h[8]; i32x4 v; } u;
  u.h[0] = (_Float16)a.x; u.h[1] = (_Float16)a.y;
  u.h[2] = (_Float16)a.z; u.h[3] = (_Float16)a.w;
  u.h[4] = (_Float16)b.x; u.h[5] = (_Float16)b.y;
  u.h[6] = (_Float16)b.z; u.h[7] = (_Float16)b.w;
  *(i32x4*)(Wh + i) = u.v;
}

__device__ inline float softplus_f(float x) {
  float e = __expf(-fabsf(x));
  return fmaxf(x, 0.f) + __logf(1.f + e);
}

// ---- fused GEMM(fp16 MFMA) + softplus-diff partial ----
// R12 geometry (proven: 0 conflicts, absmax 0.0156): block 128x256
// (N-split 2), BK=64, 32 K-steps, 8 waves 2Mx4N, wave-tile 64x64.
// R13 deltas:
//  (1) XCD pairing: bx -> r=(bx>>4)*8+(bx&7), h=(bx>>3)&1 so both N-halves
//      of a row-tile are 8 apart -> same XCD -> X re-read is L2-hit.
//  (2) B triple-buffer, prefetch distance 2: every load gets >= 1 full
//      step of flight; tail vmcnt(8) keeps A(t+2)+B(t+2) (48 KB) in
//      flight across every barrier (verified by queue induction).
//  (3) no sched_barrier / setprio / mid-step waits (m141/m190).
__global__ __launch_bounds__(512, 2) void k_main(
    const float* __restrict__ X,      // [16384][2048]
    const _Float16* __restrict__ Wh,  // [512][2048]
    const float* __restrict__ U,      // [512][2]
    const float* __restrict__ hb,     // [512]
    float* __restrict__ Dp) {         // [2][16384] partial logit-diffs
  __shared__ __align__(16) _Float16 As[2][128 * 64];  // 2 x 16 KB
  __shared__ __align__(16) _Float16 Bs[3][256 * 64];  // 3 x 32 KB
  __shared__ float sD[128];

  const int t = threadIdx.x;
  const int lane = t & 63;
  const int wid = t >> 6;   // 0..7
  const int wm = wid >> 2;  // 0..1 (M half)
  const int wn = wid & 3;   // 0..3 (N quarter)
  const int bx = blockIdx.x;
  const int rt = (bx >> 4) * 8 + (bx & 7);  // row-tile 0..127
  const int nhalf = (bx >> 3) & 1;          // pair partner is bx^8: same XCD
  const int bm0 = rt * 128;
  const int bn0 = nhalf * 256;
  const int lrow = lane & 15, lq = lane >> 4;

  if (t < 128) sD[t] = 0.f;
  __syncthreads();

  f32x4 acc[4][4];
#pragma unroll
  for (int m = 0; m < 4; ++m)
#pragma unroll
    for (int n = 0; n < 4; ++n) acc[m][n] = (f32x4){0.f, 0.f, 0.f, 0.f};

  // A staging: thread -> row t>>2 (0..127), k-chunk16 t&3. Writes 2 f16x8
  // at slots {2c, 2c+1} ^ (row&7)  (proven swizzle family, R4-R12).
  const int arow = t >> 2, ach = t & 3;
  const float* xsrc = X + (size_t)(bm0 + arow) * 2048 + ach * 16;
  const int c0 = ach * 2;
  const int aw0 = arow * 128 + (((c0) ^ (arow & 7)) << 4);
  const int aw1 = arow * 128 + (((c0 + 1) ^ (arow & 7)) << 4);

  // B staging: wave wid covers rows [wid*32, wid*32+32), 4 gld_lds of 1KB.
  // Pre-swizzled source (m173): phys slot s8 of row l8 holds chunk s8^l8.
  const int l8 = lane >> 3, s8 = lane & 7;
  const _Float16* bsrc =
      Wh + (size_t)(bn0 + wid * 32 + l8) * 2048 + (s8 ^ l8) * 8;
  char* const bd0 = (char*)&Bs[0][0] + wid * 4096;
  char* const bd1 = (char*)&Bs[1][0] + wid * 4096;
  char* const bd2 = (char*)&Bs[2][0] + wid * 4096;

  f32x4 arA[4], arB[4];  // A fp32 raw, two named sets (static idx only)

#define CVT_WRITE_A(ARC, Q) do {                                           \
    f16x8 hv0, hv1;                                                        \
    _Pragma("unroll") for (int j = 0; j < 4; ++j) {                        \
      hv0[j] = (_Float16)ARC[0][j]; hv0[j + 4] = (_Float16)ARC[1][j];      \
      hv1[j] = (_Float16)ARC[2][j]; hv1[j + 4] = (_Float16)ARC[3][j];      \
    }                                                                      \
    *(f16x8*)((char*)&As[Q][0] + aw0) = hv0;                               \
    *(f16x8*)((char*)&As[Q][0] + aw1) = hv1;                               \
  } while (0)

  // One K-step (KT): stage B(KT+2)->BWD, load A(KT+2)->ARL, cvt
  // A(KT+1)->As[Q], compute tile KT from As[P]/Bs[BR].
  // Tail: vmcnt(8) (A(KT+2)+B(KT+2) stay in flight) + lgkm(0) + barrier.
#define STEP(KT, P, Q, ARL, ARC, BR, BWD) do {                             \
    const int kb_ = ((KT) + 2 > 31) ? 31 : (KT) + 2;                       \
    _Pragma("unroll") for (int i = 0; i < 4; ++i)                          \
      GLD_LDS16(bsrc + (size_t)i * 16384 + (size_t)kb_ * 64,               \
                (BWD) + i * 1024);                                         \
    _Pragma("unroll") for (int c = 0; c < 4; ++c)                          \
      ARL[c] = *(const f32x4*)(xsrc + (size_t)kb_ * 64 + c * 4);           \
    CVT_WRITE_A(ARC, Q);                                                   \
    f16x8 fa[4][2], fb[4][2];                                              \
    _Pragma("unroll") for (int mf = 0; mf < 4; ++mf) {                     \
      int row = wm * 64 + mf * 16 + lrow;                                  \
      _Pragma("unroll") for (int ks = 0; ks < 2; ++ks) {                   \
        int off = row * 128 + (((ks * 4 + lq) ^ (row & 7)) << 4);          \
        fa[mf][ks] = *(const f16x8*)((const char*)&As[P][0] + off);        \
      }                                                                    \
    }                                                                      \
    _Pragma("unroll") for (int nf = 0; nf < 4; ++nf) {                     \
      int row = wn * 64 + nf * 16 + lrow;                                  \
      _Pragma("unroll") for (int ks = 0; ks < 2; ++ks) {                   \
        int off = row * 128 + (((ks * 4 + lq) ^ (row & 7)) << 4);          \
        fb[nf][ks] = *(const f16x8*)((const char*)&Bs[BR][0] + off);       \
      }                                                                    \
    }                                                                      \
    _Pragma("unroll") for (int ks = 0; ks < 2; ++ks)                       \
      _Pragma("unroll") for (int mf = 0; mf < 4; ++mf)                     \
        _Pragma("unroll") for (int nf = 0; nf < 4; ++nf)                   \
          acc[mf][nf] = __builtin_amdgcn_mfma_f32_16x16x32_f16(            \
              fa[mf][ks], fb[nf][ks], acc[mf][nf], 0, 0, 0);               \
    asm volatile("s_waitcnt vmcnt(8) lgkmcnt(0)" ::: "memory");            \
    __builtin_amdgcn_s_barrier();                                          \
  } while (0)

  // ---- prologue: B(0)->slot0, B(1)->slot1, A(0)->arA, A(1)->arB;
  //      cvt A(0)->As[0] (compiler waits A(0) precisely) ----
#pragma unroll
  for (int i = 0; i < 4; ++i)
    GLD_LDS16(bsrc + (size_t)i * 16384, bd0 + i * 1024);
#pragma unroll
  for (int i = 0; i < 4; ++i)
    GLD_LDS16(bsrc + (size_t)i * 16384 + 64, bd1 + i * 1024);
#pragma unroll
  for (int c = 0; c < 4; ++c) arA[c] = *(const f32x4*)(xsrc + c * 4);
#pragma unroll
  for (int c = 0; c < 4; ++c) arB[c] = *(const f32x4*)(xsrc + 64 + c * 4);
  CVT_WRITE_A(arA, 0);
  asm volatile("s_waitcnt vmcnt(4) lgkmcnt(0)" ::: "memory");  // B0,B1,A0 done
  __builtin_amdgcn_s_barrier();
  // entry: outstanding = {A(1)}; As[0], Bs[0..1] staged.

  // period-6 (A parity x B mod-3); 30 steps unrolled + 2 peeled
  for (int kt = 0; kt < 30; kt += 6) {
    STEP(kt + 0, 0, 1, arA, arB, 0, bd2);
    STEP(kt + 1, 1, 0, arB, arA, 1, bd0);
    STEP(kt + 2, 0, 1, arA, arB, 2, bd1);
    STEP(kt + 3, 1, 0, arB, arA, 0, bd2);
    STEP(kt + 4, 0, 1, arA, arB, 1, bd0);
    STEP(kt + 5, 1, 0, arB, arA, 2, bd1);
  }
  // kt=30: BR=0, BW=slot2 (dup, never read). kt=31: BR=1, BW=slot0 (dup).
  STEP(30, 0, 1, arA, arB, 0, bd2);
  STEP(31, 1, 0, arB, arA, 1, bd0);
#undef STEP
#undef CVT_WRITE_A

  // ---- epilogue: softplus-difference partial for this N-half ----
  // acc[mf][nf][r]: row = bm0 + wm*64 + mf*16 + lq*4 + r
  //                 col = bn0 + wn*64 + nf*16 + lrow
  float dpart[16];
#pragma unroll
  for (int i = 0; i < 16; ++i) dpart[i] = 0.f;
#pragma unroll
  for (int nf = 0; nf < 4; ++nf) {
    int h = bn0 + wn * 64 + nf * 16 + lrow;
    float hbv = hb[h];
    float u0 = U[2 * h], u1 = U[2 * h + 1];
#pragma unroll
    for (int mf = 0; mf < 4; ++mf)
#pragma unroll
      for (int r = 0; r < 4; ++r) {
        float pf = acc[mf][nf][r] + hbv;
        dpart[mf * 4 + r] += softplus_f(pf + u0) - softplus_f(pf + u1);
      }
  }
#pragma unroll
  for (int i = 0; i < 16; ++i) {
    float v = dpart[i];
    v += __shfl_xor(v, 1);
    v += __shfl_xor(v, 2);
    v += __shfl_xor(v, 4);
    v += __shfl_xor(v, 8);
    dpart[i] = v;
  }
  if (lrow == 0) {
#pragma unroll
    for (int mf = 0; mf < 4; ++mf)
#pragma unroll
      for (int r = 0; r < 4; ++r)
        atomicAdd(&sD[wm * 64 + mf * 16 + lq * 4 + r], dpart[mf * 4 + r]);
  }
  __syncthreads();
  if (t < 128) Dp[nhalf * 16384 + bm0 + t] = sD[t];
}

// ---- combine the two N-half partials + sigmoid ----
__global__ __launch_bounds__(256) void k_final(const float* __restrict__ Dp,
                                               const float* __restrict__ yb,
                                               float* __restrict__ out) {
  int i = blockIdx.x * 256 + threadIdx.x;  // 0..16383
  float D = Dp[i] + Dp[16384 + i] + yb[0] - yb[1];  // logit0 - logit1
  float e = __expf(-D);
  float o0 = 1.f / (1.f + e);
  float o1 = e * o0;
  *(float2*)(out + (size_t)i * 2) = make_float2(o0, o1);
}

extern "C" void kernel_launch(void* const* d_in, const int* in_sizes, int n_in,
                              void* d_out, int out_size, void* d_ws,
                              size_t ws_size, hipStream_t stream) {
  const float* X = (const float*)d_in[0];
  const float* W = (const float*)d_in[1];
  const float* U = (const float*)d_in[2];
  const float* hb = (const float*)d_in[3];
  const float* yb = (const float*)d_in[4];
  float* out = (float*)d_out;
  _Float16* Wh = (_Float16*)d_ws;                       // 2 MB
  float* Dp = (float*)((char*)d_ws + 2 * 1024 * 1024);  // 128 KB partials

  hipLaunchKernelGGL(k_cvt_w, dim3(512), dim3(256), 0, stream, W, Wh);
  hipLaunchKernelGGL(k_main, dim3(256), dim3(512), 0, stream, X, Wh, U, hb, Dp);
  hipLaunchKernelGGL(k_final, dim3(64), dim3(256), 0, stream, Dp, yb, out);
}